// Round 1
// baseline (366.002 us; speedup 1.0000x reference)
//
#include <hip/hip_runtime.h>
#include <hip/hip_bf16.h>

// Problem constants
#define B_  16
#define L_  1024
#define F_  512
#define H_  8
#define D_  64
#define M_  (B_ * L_)    // 16384 rows
#define HD_ 512

typedef __bf16 bf16x8 __attribute__((ext_vector_type(8)));
typedef __bf16 bf16x4 __attribute__((ext_vector_type(4)));
typedef float  f32x4  __attribute__((ext_vector_type(4)));

// ---------------------------------------------------------------------------
// Weight prep: Wt[n][k] = (bf16) W[k][n]  for Wq,Wk,Wv,Wo (each 512x512).
// Transposed+bf16 so GEMM B-fragment staging reads contiguous 16B along k.
// ---------------------------------------------------------------------------
__global__ __launch_bounds__(256) void wt_kernel(
    const float* __restrict__ Wq, const float* __restrict__ Wk,
    const float* __restrict__ Wv, const float* __restrict__ Wo,
    __bf16* __restrict__ Wt_all)
{
  const float* W = (blockIdx.z == 0) ? Wq : (blockIdx.z == 1) ? Wk
                 : (blockIdx.z == 2) ? Wv : Wo;
  __bf16* Wt = Wt_all + (size_t)blockIdx.z * (512 * 512);
  __shared__ float s[32][33];
  const int t = threadIdx.x;
  const int r = t >> 5, c = t & 31;
  const int k0 = blockIdx.x * 32, n0 = blockIdx.y * 32;
#pragma unroll
  for (int i = 0; i < 4; ++i)
    s[r + i * 8][c] = W[(size_t)(k0 + r + i * 8) * 512 + n0 + c];
  __syncthreads();
#pragma unroll
  for (int i = 0; i < 4; ++i)
    Wt[(size_t)(n0 + r + i * 8) * 512 + k0 + c] = (__bf16)s[c][r + i * 8];
}

// ---------------------------------------------------------------------------
// Projection GEMM: C[16384,512] = X(fp32) @ W + bias, written as bf16.
// mode 0/1: dst layout (B,H,L,D)   (q and k)
// mode 2  : dst layout (B,H,D,L)   (v transposed; contiguous along L)
// Tiles: BM=128, BN=128, BK=32; 4 waves, each computing 64x64 (4x4 MFMA tiles).
// LDS layout [ko=k/8][row][k%8] so MFMA fragment reads are contiguous b128.
// ---------------------------------------------------------------------------
__global__ __launch_bounds__(256) void gemm_proj_kernel(
    const float* __restrict__ X,    // [16384][512] fp32
    const __bf16* __restrict__ Wt,  // [512 n][512 k] bf16 (pre-transposed)
    const float* __restrict__ bias, // [512]
    __bf16* __restrict__ dst, int mode)
{
  __shared__ __align__(16) __bf16 As[4][128][8];
  __shared__ __align__(16) __bf16 Bs[4][128][8];
  const int t = threadIdx.x;
  const int m0 = blockIdx.x * 128, n0 = blockIdx.y * 128;
  const int lane = t & 63, w = t >> 6;
  const int ml = lane & 15, quad = lane >> 4;
  const int wm = w & 1, wn = w >> 1;

  f32x4 acc[4][4];
#pragma unroll
  for (int i = 0; i < 4; ++i)
#pragma unroll
    for (int j = 0; j < 4; ++j) acc[i][j] = (f32x4){0.f, 0.f, 0.f, 0.f};

  for (int k0 = 0; k0 < 512; k0 += 32) {
    __syncthreads();
#pragma unroll
    for (int i = 0; i < 2; ++i) {
      int slot = t + i * 256;
      int ko = slot & 3, row = slot >> 2;  // 128 rows x 4 ko-groups
      const float* src = X + (size_t)(m0 + row) * 512 + k0 + ko * 8;
      float4 f0 = *(const float4*)src;
      float4 f1 = *(const float4*)(src + 4);
      bf16x8 v;
      v[0] = (__bf16)f0.x; v[1] = (__bf16)f0.y; v[2] = (__bf16)f0.z; v[3] = (__bf16)f0.w;
      v[4] = (__bf16)f1.x; v[5] = (__bf16)f1.y; v[6] = (__bf16)f1.z; v[7] = (__bf16)f1.w;
      *(bf16x8*)&As[ko][row][0] = v;
      *(bf16x8*)&Bs[ko][row][0] =
          *(const bf16x8*)&Wt[(size_t)(n0 + row) * 512 + k0 + ko * 8];
    }
    __syncthreads();
    bf16x8 a[4], b[4];
#pragma unroll
    for (int mt = 0; mt < 4; ++mt)
      a[mt] = *(const bf16x8*)&As[quad][wm * 64 + mt * 16 + ml][0];
#pragma unroll
    for (int nt = 0; nt < 4; ++nt)
      b[nt] = *(const bf16x8*)&Bs[quad][wn * 64 + nt * 16 + ml][0];
#pragma unroll
    for (int mt = 0; mt < 4; ++mt)
#pragma unroll
      for (int nt = 0; nt < 4; ++nt)
        acc[mt][nt] =
            __builtin_amdgcn_mfma_f32_16x16x32_bf16(a[mt], b[nt], acc[mt][nt], 0, 0, 0);
  }

  // Epilogue. C/D layout: col = lane&15, row = quad*4 + reg (m89-verified).
#pragma unroll
  for (int nt = 0; nt < 4; ++nt) {
    int col = n0 + wn * 64 + nt * 16 + ml;
    float bv = bias[col];
    int h = col >> 6, d = col & 63;
#pragma unroll
    for (int mt = 0; mt < 4; ++mt) {
      int row0 = m0 + wm * 64 + mt * 16 + quad * 4;  // 4 consecutive rows
      int bz = row0 >> 10;
      int l0 = row0 & 1023;
      if (mode == 2) {
        // v: (B,H,D,L) — 4 consecutive l per lane -> one 8B store
        bf16x4 pk;
#pragma unroll
        for (int r = 0; r < 4; ++r) pk[r] = (__bf16)(acc[mt][nt][r] + bv);
        size_t idx = ((size_t)(bz * H_ + h) * D_ + d) * L_ + l0;
        *(bf16x4*)&dst[idx] = pk;
      } else {
        // q/k: (B,H,L,D)
        size_t base = ((size_t)(bz * H_ + h) * L_ + l0) * D_ + d;
#pragma unroll
        for (int r = 0; r < 4; ++r)
          dst[base + (size_t)r * D_] = (__bf16)(acc[mt][nt][r] + bv);
      }
    }
  }
}

// ---------------------------------------------------------------------------
// Flash attention with toeplitz bias. One block per (q-tile of 64, h, b).
// 4 waves; wave w owns q-rows w*16..w*16+15. Online softmax state lives
// per-lane (row = quad*4+reg matches the MFMA C/D layout, so no LDS state).
// ---------------------------------------------------------------------------
__global__ __launch_bounds__(256) void attn_kernel(
    const __bf16* __restrict__ qg,    // [B][H][L][D]
    const __bf16* __restrict__ kg,    // [B][H][L][D]
    const __bf16* __restrict__ vg,    // [B][H][D][L]
    const float* __restrict__ toep_g, // [H][4096]
    __bf16* __restrict__ xg)          // [B*L][512]
{
  __shared__ float toep[4096];
  __shared__ __align__(16) __bf16 Qs[8][64][8];  // [d/8][qrow][d%8]
  __shared__ __align__(16) __bf16 Ks[8][64][8];  // [d/8][krow][d%8]
  __shared__ __align__(16) __bf16 Vs[8][64][8];  // [key/8][d][key%8]
  __shared__ __align__(16) __bf16 Ps[8][64][8];  // [key/8][qrow][key%8]

  const int t = threadIdx.x;
  const int q0 = blockIdx.x * 64;
  const int h = blockIdx.y;
  const int bz = blockIdx.z;
  const int lane = t & 63, w = t >> 6;
  const int ml = lane & 15, quad = lane >> 4;

  // toeplitz table for this head -> LDS (16 KB)
  {
    const float4* src = (const float4*)(toep_g + (size_t)h * 4096);
    float4* dstl = (float4*)toep;
    for (int i = t; i < 1024; i += 256) dstl[i] = src[i];
  }
  // Q tile
  const size_t qkbase = (size_t)(bz * H_ + h) * L_ * D_;
#pragma unroll
  for (int i = 0; i < 2; ++i) {
    int slot = t + i * 256;
    int ko = slot & 7, row = slot >> 3;
    *(bf16x8*)&Qs[ko][row][0] =
        *(const bf16x8*)&qg[qkbase + (size_t)(q0 + row) * D_ + ko * 8];
  }

  float mrow[4], lrow[4];
  f32x4 o[4];
#pragma unroll
  for (int r = 0; r < 4; ++r) { mrow[r] = -1e30f; lrow[r] = 0.f; }
#pragma unroll
  for (int dt = 0; dt < 4; ++dt) o[dt] = (f32x4){0.f, 0.f, 0.f, 0.f};

  const size_t vbase = (size_t)(bz * H_ + h) * D_ * L_;

  for (int k0 = 0; k0 < L_; k0 += 64) {
    __syncthreads();  // protect Ks/Vs (and Qs on first pass)
#pragma unroll
    for (int i = 0; i < 2; ++i) {
      int slot = t + i * 256;
      int ko = slot & 7, row = slot >> 3;
      *(bf16x8*)&Ks[ko][row][0] =
          *(const bf16x8*)&kg[qkbase + (size_t)(k0 + row) * D_ + ko * 8];
      // Vs[key/8][d=row][key%8] <- vg[b,h,d=row, k0+ko*8..+7] (contiguous)
      *(bf16x8*)&Vs[ko][row][0] =
          *(const bf16x8*)&vg[vbase + (size_t)row * L_ + k0 + ko * 8];
    }
    __syncthreads();

    // S = Q K^T  (k-dim = D = 64 -> 2 MFMAs per 16x16 tile)
    f32x4 s[4];
    bf16x8 aq0 = *(const bf16x8*)&Qs[quad][w * 16 + ml][0];
    bf16x8 aq1 = *(const bf16x8*)&Qs[4 + quad][w * 16 + ml][0];
#pragma unroll
    for (int nt = 0; nt < 4; ++nt) {
      bf16x8 bk0 = *(const bf16x8*)&Ks[quad][nt * 16 + ml][0];
      bf16x8 bk1 = *(const bf16x8*)&Ks[4 + quad][nt * 16 + ml][0];
      s[nt] = (f32x4){0.f, 0.f, 0.f, 0.f};
      s[nt] = __builtin_amdgcn_mfma_f32_16x16x32_bf16(aq0, bk0, s[nt], 0, 0, 0);
      s[nt] = __builtin_amdgcn_mfma_f32_16x16x32_bf16(aq1, bk1, s[nt], 0, 0, 0);
    }

    // bias + scale
    float sv[4][4];
#pragma unroll
    for (int nt = 0; nt < 4; ++nt) {
      int kj = k0 + nt * 16 + ml;
      int kx = kj >> 5, ky = kj & 31;
#pragma unroll
      for (int r = 0; r < 4; ++r) {
        int qi = q0 + w * 16 + quad * 4 + r;
        int dx = (qi >> 5) - kx + 32;
        int dy = (qi & 31) - ky + 32;
        sv[nt][r] = s[nt][r] * 0.125f + toep[dx * 64 + dy];
      }
    }

    // online softmax (row r lives in the 16 lanes of this quad)
#pragma unroll
    for (int r = 0; r < 4; ++r) {
      float mx = fmaxf(fmaxf(sv[0][r], sv[1][r]), fmaxf(sv[2][r], sv[3][r]));
#pragma unroll
      for (int off = 1; off < 16; off <<= 1) mx = fmaxf(mx, __shfl_xor(mx, off));
      float mnew = fmaxf(mrow[r], mx);
      float alpha = __expf(mrow[r] - mnew);
      float ssum = 0.f;
#pragma unroll
      for (int nt = 0; nt < 4; ++nt) {
        float p = __expf(sv[nt][r] - mnew);
        sv[nt][r] = p;
        ssum += p;
      }
#pragma unroll
      for (int off = 1; off < 16; off <<= 1) ssum += __shfl_xor(ssum, off);
      lrow[r] = lrow[r] * alpha + ssum;
      mrow[r] = mnew;
#pragma unroll
      for (int dt = 0; dt < 4; ++dt) o[dt][r] *= alpha;
    }

    // P -> LDS in A-operand layout [key/8][qrow][key%8]
#pragma unroll
    for (int nt = 0; nt < 4; ++nt)
#pragma unroll
      for (int r = 0; r < 4; ++r)
        Ps[nt * 2 + (ml >> 3)][w * 16 + quad * 4 + r][ml & 7] = (__bf16)sv[nt][r];
    __syncthreads();

    // O += P @ V
#pragma unroll
    for (int kb = 0; kb < 2; ++kb) {
      bf16x8 ap = *(const bf16x8*)&Ps[kb * 4 + quad][w * 16 + ml][0];
#pragma unroll
      for (int dt = 0; dt < 4; ++dt) {
        bf16x8 bvf = *(const bf16x8*)&Vs[kb * 4 + quad][dt * 16 + ml][0];
        o[dt] = __builtin_amdgcn_mfma_f32_16x16x32_bf16(ap, bvf, o[dt], 0, 0, 0);
      }
    }
  }

  // epilogue: x[b*L+row][h*64+d] = O/l
#pragma unroll
  for (int dt = 0; dt < 4; ++dt)
#pragma unroll
    for (int r = 0; r < 4; ++r) {
      int row = q0 + w * 16 + quad * 4 + r;
      float val = o[dt][r] / lrow[r];
      xg[(size_t)(bz * L_ + row) * 512 + h * 64 + dt * 16 + ml] = (__bf16)val;
    }
}

// ---------------------------------------------------------------------------
// Output GEMM: out[16384,512] (fp32) = Xattn(bf16) @ Wo + bo
// ---------------------------------------------------------------------------
__global__ __launch_bounds__(256) void gemm_out_kernel(
    const __bf16* __restrict__ Xb,  // [16384][512] bf16
    const __bf16* __restrict__ Wt,  // [512 n][512 k] bf16
    const float* __restrict__ bo,   // [512]
    float* __restrict__ out)        // [16384][512] fp32
{
  __shared__ __align__(16) __bf16 As[4][128][8];
  __shared__ __align__(16) __bf16 Bs[4][128][8];
  const int t = threadIdx.x;
  const int m0 = blockIdx.x * 128, n0 = blockIdx.y * 128;
  const int lane = t & 63, w = t >> 6;
  const int ml = lane & 15, quad = lane >> 4;
  const int wm = w & 1, wn = w >> 1;

  f32x4 acc[4][4];
#pragma unroll
  for (int i = 0; i < 4; ++i)
#pragma unroll
    for (int j = 0; j < 4; ++j) acc[i][j] = (f32x4){0.f, 0.f, 0.f, 0.f};

  for (int k0 = 0; k0 < 512; k0 += 32) {
    __syncthreads();
#pragma unroll
    for (int i = 0; i < 2; ++i) {
      int slot = t + i * 256;
      int ko = slot & 3, row = slot >> 2;
      *(bf16x8*)&As[ko][row][0] =
          *(const bf16x8*)&Xb[(size_t)(m0 + row) * 512 + k0 + ko * 8];
      *(bf16x8*)&Bs[ko][row][0] =
          *(const bf16x8*)&Wt[(size_t)(n0 + row) * 512 + k0 + ko * 8];
    }
    __syncthreads();
    bf16x8 a[4], b[4];
#pragma unroll
    for (int mt = 0; mt < 4; ++mt)
      a[mt] = *(const bf16x8*)&As[quad][wm * 64 + mt * 16 + ml][0];
#pragma unroll
    for (int nt = 0; nt < 4; ++nt)
      b[nt] = *(const bf16x8*)&Bs[quad][wn * 64 + nt * 16 + ml][0];
#pragma unroll
    for (int mt = 0; mt < 4; ++mt)
#pragma unroll
      for (int nt = 0; nt < 4; ++nt)
        acc[mt][nt] =
            __builtin_amdgcn_mfma_f32_16x16x32_bf16(a[mt], b[nt], acc[mt][nt], 0, 0, 0);
  }

#pragma unroll
  for (int nt = 0; nt < 4; ++nt) {
    int col = n0 + wn * 64 + nt * 16 + ml;
    float bv = bo[col];
#pragma unroll
    for (int mt = 0; mt < 4; ++mt) {
      int row0 = m0 + wm * 64 + mt * 16 + quad * 4;
#pragma unroll
      for (int r = 0; r < 4; ++r)
        out[(size_t)(row0 + r) * 512 + col] = acc[mt][nt][r] + bv;
    }
  }
}

// ---------------------------------------------------------------------------
extern "C" void kernel_launch(void* const* d_in, const int* in_sizes, int n_in,
                              void* d_out, int out_size, void* d_ws, size_t ws_size,
                              hipStream_t stream) {
  const float* inputs_q  = (const float*)d_in[0];
  const float* inputs_kv = (const float*)d_in[1];
  const float* Wq = (const float*)d_in[2];
  const float* bq = (const float*)d_in[3];
  const float* Wk = (const float*)d_in[4];
  const float* bk = (const float*)d_in[5];
  const float* Wv = (const float*)d_in[6];
  const float* bv = (const float*)d_in[7];
  const float* Wo = (const float*)d_in[8];
  const float* bo = (const float*)d_in[9];
  const float* toep = (const float*)d_in[10];
  float* out = (float*)d_out;

  // Workspace layout (bytes):
  //   q   (B,H,L,D) bf16 : 16 MiB @ 0
  //   k   (B,H,L,D) bf16 : 16 MiB @ 16777216
  //   v   (B,H,D,L) bf16 : 16 MiB @ 33554432
  //   x   (B*L,512) bf16 : 16 MiB @ 50331648
  //   Wt  4x512x512 bf16 :  2 MiB @ 67108864
  char* ws = (char*)d_ws;
  __bf16* qb = (__bf16*)(ws);
  __bf16* kb = (__bf16*)(ws + 16777216);
  __bf16* vb = (__bf16*)(ws + 33554432);
  __bf16* xb = (__bf16*)(ws + 50331648);
  __bf16* Wt = (__bf16*)(ws + 67108864);

  wt_kernel<<<dim3(16, 16, 4), 256, 0, stream>>>(Wq, Wk, Wv, Wo, Wt);
  gemm_proj_kernel<<<dim3(128, 4), 256, 0, stream>>>(inputs_q,  Wt + 0 * 262144, bq, qb, 0);
  gemm_proj_kernel<<<dim3(128, 4), 256, 0, stream>>>(inputs_kv, Wt + 1 * 262144, bk, kb, 1);
  gemm_proj_kernel<<<dim3(128, 4), 256, 0, stream>>>(inputs_kv, Wt + 2 * 262144, bv, vb, 2);
  attn_kernel<<<dim3(16, 8, 16), 256, 0, stream>>>(qb, kb, vb, toep, xb);
  gemm_out_kernel<<<dim3(128, 4), 256, 0, stream>>>(xb, Wt + 3 * 262144, bo, out);
}